// Round 1
// baseline (418.728 us; speedup 1.0000x reference)
//
#include <hip/hip_runtime.h>
#include <hip/hip_bf16.h>

typedef __attribute__((ext_vector_type(8))) short short8;
typedef __attribute__((ext_vector_type(4))) float f32x4;
typedef unsigned short u16;

__device__ __forceinline__ float b2f(u16 h) {
    unsigned u = ((unsigned)h) << 16;
    float f; __builtin_memcpy(&f, &u, 4); return f;
}
__device__ __forceinline__ u16 f2b(float f) {
    unsigned u; __builtin_memcpy(&u, &f, 4);
    unsigned r = u + 0x7FFFu + ((u >> 16) & 1u);
    return (u16)(r >> 16);
}

// ---------------- problem constants ----------------
#define M_VALID 2640          // B*S*T tokens
#define M_PAD   2688          // 21 * 128
#define K1      3096          // 3072 + 24
#define K1P     3104          // padded to multiple of 32
#define DH      1024
#define CIMG    3072
#define NKV     2656          // 83 * 32 (kv padded)
#define NHEAD   16
#define DD      64

// ---------------- build fused input (bf16) ----------------
__global__ __launch_bounds__(256) void build_fused_kernel(
    const float* __restrict__ x, const float* __restrict__ cond,
    u16* __restrict__ fused)
{
    int n = blockIdx.x;
    int tid = threadIdx.x;
    const float* xr = x + (size_t)n * CIMG;
    u16* fr = fused + (size_t)n * K1P;
    for (int c = tid * 4; c < CIMG; c += 1024) {
        float4 v = *(const float4*)(xr + c);
        fr[c] = f2b(v.x); fr[c+1] = f2b(v.y); fr[c+2] = f2b(v.z); fr[c+3] = f2b(v.w);
    }
    if (tid < 8) {
        int t = n % 3;
        for (int jj = 0; jj < 4; jj++) {
            int j = tid * 4 + jj;
            int c = CIMG + j;
            float val = 0.f;
            if (j < 24) {
                int f = t * 4 + (j >> 1);          // row in mouse_padded (20 rows, first 8 zero)
                if (f >= 8) val = cond[(f - 8) * 2 + (j & 1)];
            }
            fr[c] = f2b(val);
        }
    }
}

// ---------------- transpose fp32 [K][N] -> bf16 [N][ldt] ----------------
__global__ __launch_bounds__(256) void transpose_bf16_kernel(
    const float* __restrict__ W, u16* __restrict__ Wt, int K, int N, int ldt)
{
    __shared__ float t[32][33];
    int n0 = blockIdx.x * 32, k0 = blockIdx.y * 32;
    int x = threadIdx.x & 31, y0 = threadIdx.x >> 5;   // 32x8
    for (int yy = y0; yy < 32; yy += 8) {
        int k = k0 + yy, n = n0 + x;
        t[yy][x] = (k < K && n < N) ? W[(size_t)k * N + n] : 0.f;
    }
    __syncthreads();
    for (int yy = y0; yy < 32; yy += 8) {
        int n = n0 + yy, k = k0 + x;
        if (n < N && k < ldt) Wt[(size_t)n * ldt + k] = f2b(t[x][yy]);
    }
}

// ---------------- GEMM: C[M][N] = A[M][K] @ Bt[N][K]^T  (bf16 in, f32 acc) ----------------
// EPI 0: +bias, tanh-GELU -> bf16       EPI 1: +bias -> bf16
// EPI 2: +bias + resid -> f32 (rows < Mvalid)
template<int EPI>
__global__ __launch_bounds__(256) void gemm_kernel(
    const u16* __restrict__ A, const u16* __restrict__ Bt,
    const float* __restrict__ bias, const float* __restrict__ resid,
    u16* __restrict__ Cb, float* __restrict__ Cf,
    int N, int K, int Mvalid)
{
    __shared__ u16 As[128 * 32];
    __shared__ u16 Bs[128 * 32];
    const int tid = threadIdx.x;
    const int lane = tid & 63, wid = tid >> 6;
    const int l15 = lane & 15, l4 = lane >> 4;
    const int m0 = blockIdx.y * 128, n0 = blockIdx.x * 128;
    const int wr = (wid >> 1) * 64, wc = (wid & 1) * 64;

    f32x4 acc[4][4];
#pragma unroll
    for (int i = 0; i < 4; i++)
#pragma unroll
        for (int j = 0; j < 4; j++) acc[i][j] = (f32x4){0.f, 0.f, 0.f, 0.f};

    const int r0 = tid >> 2, sg = (tid & 3) * 8;

    for (int k0 = 0; k0 < K; k0 += 32) {
        __syncthreads();
        {
            const u16* ga = A + (size_t)(m0 + r0) * K + k0 + sg;
            short8 a0 = *(const short8*)ga;
            short8 a1 = *(const short8*)(ga + (size_t)64 * K);
            const u16* gb = Bt + (size_t)(n0 + r0) * K + k0 + sg;
            short8 b0 = *(const short8*)gb;
            short8 b1 = *(const short8*)(gb + (size_t)64 * K);
            *(short8*)(&As[r0 * 32 + sg]) = a0;
            *(short8*)(&As[(r0 + 64) * 32 + sg]) = a1;
            *(short8*)(&Bs[r0 * 32 + sg]) = b0;
            *(short8*)(&Bs[(r0 + 64) * 32 + sg]) = b1;
        }
        __syncthreads();
        short8 af[4], bfr[4];
#pragma unroll
        for (int i = 0; i < 4; i++)
            af[i] = *(const short8*)(&As[(wr + i * 16 + l15) * 32 + l4 * 8]);
#pragma unroll
        for (int j = 0; j < 4; j++)
            bfr[j] = *(const short8*)(&Bs[(wc + j * 16 + l15) * 32 + l4 * 8]);
#pragma unroll
        for (int i = 0; i < 4; i++)
#pragma unroll
            for (int j = 0; j < 4; j++)
                acc[i][j] = __builtin_amdgcn_mfma_f32_16x16x32_bf16(af[i], bfr[j], acc[i][j], 0, 0, 0);
    }

#pragma unroll
    for (int i = 0; i < 4; i++) {
#pragma unroll
        for (int j = 0; j < 4; j++) {
#pragma unroll
            for (int r = 0; r < 4; r++) {
                int row = m0 + wr + i * 16 + l4 * 4 + r;
                int col = n0 + wc + j * 16 + l15;
                float v = acc[i][j][r] + bias[col];
                if (EPI == 0) {
                    float t = v + 0.044715f * v * v * v;
                    float g = 0.5f * v * (1.0f + tanhf(0.7978845608028654f * t));
                    Cb[(size_t)row * N + col] = f2b(g);
                } else if (EPI == 1) {
                    Cb[(size_t)row * N + col] = f2b(v);
                } else {
                    if (row < Mvalid)
                        Cf[(size_t)row * N + col] = v + resid[(size_t)row * N + col];
                }
            }
        }
    }
}

// ---------------- LayerNorm over 1024 (bf16 -> bf16) ----------------
__global__ __launch_bounds__(256) void ln_kernel(
    const u16* __restrict__ h2, const float* __restrict__ g,
    const float* __restrict__ b, u16* __restrict__ out)
{
    int row = blockIdx.x;
    int tid = threadIdx.x;
    const u16* p = h2 + (size_t)row * DH;
    float v[4];
#pragma unroll
    for (int i = 0; i < 4; i++) v[i] = b2f(p[tid * 4 + i]);
    float s1 = v[0] + v[1] + v[2] + v[3];
    float s2 = v[0]*v[0] + v[1]*v[1] + v[2]*v[2] + v[3]*v[3];
    for (int m = 1; m < 64; m <<= 1) { s1 += __shfl_xor(s1, m); s2 += __shfl_xor(s2, m); }
    __shared__ float a1[4], a2[4];
    int w = tid >> 6;
    if ((tid & 63) == 0) { a1[w] = s1; a2[w] = s2; }
    __syncthreads();
    s1 = a1[0] + a1[1] + a1[2] + a1[3];
    s2 = a2[0] + a2[1] + a2[2] + a2[3];
    float mean = s1 * (1.0f / 1024.0f);
    float var = s2 * (1.0f / 1024.0f) - mean * mean;
    float rs = rsqrtf(var + 1e-5f);
    u16* q = out + (size_t)row * DH;
#pragma unroll
    for (int i = 0; i < 4; i++) {
        int c = tid * 4 + i;
        q[c] = f2b((v[i] - mean) * rs * g[c] + b[c]);
    }
}

// ---------------- RMSNorm q,k + split + V transpose ----------------
__global__ __launch_bounds__(256) void rmsnorm_kernel(
    const u16* __restrict__ qkv, const float* __restrict__ qw, const float* __restrict__ kw,
    u16* __restrict__ qb, u16* __restrict__ kb, u16* __restrict__ vt)
{
    int n = blockIdx.x;
    int lane = threadIdx.x & 63, w = threadIdx.x >> 6;
#pragma unroll
    for (int hh = 0; hh < 4; hh++) {
        int h = w * 4 + hh;
        float qv = b2f(qkv[(size_t)n * 3072 + h * 64 + lane]);
        float kv = b2f(qkv[(size_t)n * 3072 + 1024 + h * 64 + lane]);
        float vv = b2f(qkv[(size_t)n * 3072 + 2048 + h * 64 + lane]);
        float sq = qv * qv, sk = kv * kv;
        for (int m = 1; m < 64; m <<= 1) { sq += __shfl_xor(sq, m); sk += __shfl_xor(sk, m); }
        float rq = rsqrtf(sq * (1.0f / 64.0f) + 1e-6f);
        float rk = rsqrtf(sk * (1.0f / 64.0f) + 1e-6f);
        qb[(size_t)n * DH + h * 64 + lane] = f2b(qv * rq * qw[lane]);
        kb[(size_t)n * DH + h * 64 + lane] = f2b(kv * rk * kw[lane]);
        vt[(size_t)(h * 64 + lane) * NKV + n] = f2b(vv);
    }
}

// ---------------- flash attention: 1 wave per (16-query block, head) ----------------
__global__ __launch_bounds__(64) void attn_kernel(
    const u16* __restrict__ Q, const u16* __restrict__ Kb,
    const u16* __restrict__ Vt, u16* __restrict__ O)
{
    const int qb = blockIdx.x, h = blockIdx.y;
    const int lane = threadIdx.x;
    const int l15 = lane & 15, l4 = lane >> 4;
    const int n0 = qb * 16;
    __shared__ u16 P[16 * 32];

    short8 qa[2];
#pragma unroll
    for (int d = 0; d < 2; d++)
        qa[d] = *(const short8*)(Q + (size_t)(n0 + l15) * DH + h * 64 + d * 32 + l4 * 8);

    float mr[4], lr[4];
    f32x4 oa[4];
#pragma unroll
    for (int r = 0; r < 4; r++) { mr[r] = -3.0e38f; lr[r] = 0.f; }
#pragma unroll
    for (int f = 0; f < 4; f++) oa[f] = (f32x4){0.f, 0.f, 0.f, 0.f};

    const f32x4 zero4 = (f32x4){0.f, 0.f, 0.f, 0.f};

    for (int k0 = 0; k0 < NKV; k0 += 32) {
        f32x4 s[2];
#pragma unroll
        for (int nf = 0; nf < 2; nf++) {
            short8 kf0 = *(const short8*)(Kb + (size_t)(k0 + nf * 16 + l15) * DH + h * 64 + l4 * 8);
            short8 kf1 = *(const short8*)(Kb + (size_t)(k0 + nf * 16 + l15) * DH + h * 64 + 32 + l4 * 8);
            s[nf] = __builtin_amdgcn_mfma_f32_16x16x32_bf16(qa[0], kf0, zero4, 0, 0, 0);
            s[nf] = __builtin_amdgcn_mfma_f32_16x16x32_bf16(qa[1], kf1, s[nf], 0, 0, 0);
        }
#pragma unroll
        for (int nf = 0; nf < 2; nf++) {
            int key = k0 + nf * 16 + l15;
            float msk = (key < M_VALID) ? 0.f : -3.0e38f;
#pragma unroll
            for (int r = 0; r < 4; r++) s[nf][r] = s[nf][r] * 0.125f + msk;
        }
        float pv[2][4];
#pragma unroll
        for (int r = 0; r < 4; r++) {
            float rowmax = fmaxf(s[0][r], s[1][r]);
#pragma unroll
            for (int m = 1; m < 16; m <<= 1) rowmax = fmaxf(rowmax, __shfl_xor(rowmax, m, 16));
            float mn = fmaxf(mr[r], rowmax);
            float p0 = __expf(s[0][r] - mn), p1 = __expf(s[1][r] - mn);
            float rs = p0 + p1;
#pragma unroll
            for (int m = 1; m < 16; m <<= 1) rs += __shfl_xor(rs, m, 16);
            float corr = __expf(mr[r] - mn);
            lr[r] = lr[r] * corr + rs;
            mr[r] = mn;
            pv[0][r] = p0; pv[1][r] = p1;
#pragma unroll
            for (int f = 0; f < 4; f++) oa[f][r] *= corr;
        }
        __syncthreads();
#pragma unroll
        for (int nf = 0; nf < 2; nf++)
#pragma unroll
            for (int r = 0; r < 4; r++)
                P[(l4 * 4 + r) * 32 + nf * 16 + l15] = f2b(pv[nf][r]);
        __syncthreads();
        short8 pa = *(const short8*)(&P[l15 * 32 + l4 * 8]);
#pragma unroll
        for (int f = 0; f < 4; f++) {
            short8 vb = *(const short8*)(Vt + (size_t)(h * 64 + f * 16 + l15) * NKV + k0 + l4 * 8);
            oa[f] = __builtin_amdgcn_mfma_f32_16x16x32_bf16(pa, vb, oa[f], 0, 0, 0);
        }
    }
#pragma unroll
    for (int r = 0; r < 4; r++) {
        int n = n0 + l4 * 4 + r;
        int mrow = (n % 3) * 880 + n / 3;   // (S,T) -> (T,S) permute
        float inv = 1.0f / lr[r];
#pragma unroll
        for (int f = 0; f < 4; f++)
            O[(size_t)mrow * DH + h * 64 + f * 16 + l15] = f2b(oa[f][r] * inv);
    }
}

// ---------------- launch ----------------
extern "C" void kernel_launch(void* const* d_in, const int* in_sizes, int n_in,
                              void* d_out, int out_size, void* d_ws, size_t ws_size,
                              hipStream_t stream)
{
    const float* x      = (const float*)d_in[0];
    const float* cond   = (const float*)d_in[1];
    const float* w1     = (const float*)d_in[2];
    const float* b1     = (const float*)d_in[3];
    const float* w2     = (const float*)d_in[4];
    const float* b2     = (const float*)d_in[5];
    const float* ln_g   = (const float*)d_in[6];
    const float* ln_b   = (const float*)d_in[7];
    const float* wqkv   = (const float*)d_in[8];
    const float* bqkv   = (const float*)d_in[9];
    const float* qn_w   = (const float*)d_in[10];
    const float* kn_w   = (const float*)d_in[11];
    const float* wproj  = (const float*)d_in[12];
    const float* bproj  = (const float*)d_in[13];
    float* out = (float*)d_out;

    char* ws = (char*)d_ws;
    size_t off = 0;
    auto alloc = [&](size_t bytes) { size_t o = off; off += (bytes + 255) & ~(size_t)255; return o; };

    size_t off_fused  = alloc((size_t)M_PAD * K1P * 2);
    size_t off_w1t    = alloc((size_t)DH * K1P * 2);
    size_t off_w2t    = alloc((size_t)DH * DH * 2);
    size_t off_wqkvt  = alloc((size_t)3072 * DH * 2);
    size_t off_wprojt = alloc((size_t)CIMG * DH * 2);
    size_t off_h1     = alloc((size_t)M_PAD * DH * 2);
    size_t off_h2     = alloc((size_t)M_PAD * DH * 2);
    size_t off_h2ln   = alloc((size_t)M_PAD * DH * 2);
    size_t off_qkv    = alloc((size_t)M_PAD * 3072 * 2);
    size_t off_qbf    = alloc((size_t)M_VALID * DH * 2);
    size_t off_kbf    = alloc((size_t)NKV * DH * 2);
    size_t off_vt     = alloc((size_t)DH * NKV * 2);
    size_t off_obf    = alloc((size_t)M_PAD * DH * 2);
    (void)ws_size;

    u16* fused  = (u16*)(ws + off_fused);
    u16* w1t    = (u16*)(ws + off_w1t);
    u16* w2t    = (u16*)(ws + off_w2t);
    u16* wqkvt  = (u16*)(ws + off_wqkvt);
    u16* wprojt = (u16*)(ws + off_wprojt);
    u16* h1     = (u16*)(ws + off_h1);
    u16* h2     = (u16*)(ws + off_h2);
    u16* h2ln   = (u16*)(ws + off_h2ln);
    u16* qkvb   = (u16*)(ws + off_qkv);
    u16* qbf    = (u16*)(ws + off_qbf);
    u16* kbf    = (u16*)(ws + off_kbf);
    u16* vt     = (u16*)(ws + off_vt);
    u16* obf    = (u16*)(ws + off_obf);

    // zero pad regions (re-done every launch: deterministic)
    hipMemsetAsync(ws + off_fused + (size_t)M_VALID * K1P * 2, 0, (size_t)(M_PAD - M_VALID) * K1P * 2, stream);
    hipMemsetAsync(ws + off_kbf + (size_t)M_VALID * DH * 2, 0, (size_t)(NKV - M_VALID) * DH * 2, stream);
    hipMemsetAsync(ws + off_vt, 0, (size_t)DH * NKV * 2, stream);
    hipMemsetAsync(ws + off_obf + (size_t)M_VALID * DH * 2, 0, (size_t)(M_PAD - M_VALID) * DH * 2, stream);

    build_fused_kernel<<<M_VALID, 256, 0, stream>>>(x, cond, fused);
    transpose_bf16_kernel<<<dim3(DH / 32, K1P / 32), 256, 0, stream>>>(w1, w1t, K1, DH, K1P);
    transpose_bf16_kernel<<<dim3(DH / 32, DH / 32), 256, 0, stream>>>(w2, w2t, DH, DH, DH);
    transpose_bf16_kernel<<<dim3(3072 / 32, DH / 32), 256, 0, stream>>>(wqkv, wqkvt, DH, 3072, DH);
    transpose_bf16_kernel<<<dim3(CIMG / 32, DH / 32), 256, 0, stream>>>(wproj, wprojt, DH, CIMG, DH);

    gemm_kernel<0><<<dim3(DH / 128, M_PAD / 128), 256, 0, stream>>>(fused, w1t, b1, nullptr, h1, nullptr, DH, K1P, M_PAD);
    gemm_kernel<1><<<dim3(DH / 128, M_PAD / 128), 256, 0, stream>>>(h1, w2t, b2, nullptr, h2, nullptr, DH, DH, M_PAD);
    ln_kernel<<<M_PAD, 256, 0, stream>>>(h2, ln_g, ln_b, h2ln);
    gemm_kernel<1><<<dim3(3072 / 128, M_PAD / 128), 256, 0, stream>>>(h2ln, wqkvt, bqkv, nullptr, qkvb, nullptr, 3072, DH, M_PAD);
    rmsnorm_kernel<<<M_VALID, 256, 0, stream>>>(qkvb, qn_w, kn_w, qbf, kbf, vt);
    attn_kernel<<<dim3(M_VALID / 16, NHEAD), 64, 0, stream>>>(qbf, kbf, vt, obf);
    gemm_kernel<2><<<dim3(CIMG / 128, M_PAD / 128), 256, 0, stream>>>(obf, wprojt, bproj, x, nullptr, out, CIMG, DH, M_VALID);
}

// Round 2
// 342.860 us; speedup vs baseline: 1.2213x; 1.2213x over previous
//
#include <hip/hip_runtime.h>
#include <hip/hip_bf16.h>

typedef __attribute__((ext_vector_type(8))) short short8;
typedef __attribute__((ext_vector_type(4))) short short4v;
typedef __attribute__((ext_vector_type(4))) float f32x4;
typedef __attribute__((ext_vector_type(16))) float f32x16;
typedef unsigned short u16;

__device__ __forceinline__ float b2f(u16 h) {
    unsigned u = ((unsigned)h) << 16;
    float f; __builtin_memcpy(&f, &u, 4); return f;
}
__device__ __forceinline__ u16 f2b(float f) {
    unsigned u; __builtin_memcpy(&u, &f, 4);
    unsigned r = u + 0x7FFFu + ((u >> 16) & 1u);
    return (u16)(r >> 16);
}
__device__ __forceinline__ void gload16(const void* g, void* l) {
    __builtin_amdgcn_global_load_lds(
        (const __attribute__((address_space(1))) unsigned*)g,
        (__attribute__((address_space(3))) unsigned*)l, 16, 0, 0);
}

// ---------------- problem constants ----------------
#define M_VALID 2640          // B*S*T tokens
#define M_PAD   2688          // 21 * 128
#define K1      3096          // 3072 + 24
#define K1P     3104          // padded to multiple of 32
#define DH      1024
#define CIMG    3072
#define NKV     2656          // 83 * 32 (kv padded)
#define NHEAD   16
#define QT      83            // ceil(2640/32) q-tiles

// ---------------- build fused input (bf16) ----------------
__global__ __launch_bounds__(256) void build_fused_kernel(
    const float* __restrict__ x, const float* __restrict__ cond,
    u16* __restrict__ fused)
{
    int n = blockIdx.x;
    int tid = threadIdx.x;
    const float* xr = x + (size_t)n * CIMG;
    u16* fr = fused + (size_t)n * K1P;
    for (int c = tid * 4; c < CIMG; c += 1024) {
        float4 v = *(const float4*)(xr + c);
        short4v w;
        w[0] = (short)f2b(v.x); w[1] = (short)f2b(v.y);
        w[2] = (short)f2b(v.z); w[3] = (short)f2b(v.w);
        *(short4v*)(fr + c) = w;
    }
    if (tid < 8) {
        int t = n % 3;
        short4v w;
        for (int jj = 0; jj < 4; jj++) {
            int j = tid * 4 + jj;
            float val = 0.f;
            if (j < 24) {
                int f = t * 4 + (j >> 1);          // row in mouse_padded (20 rows, first 8 zero)
                if (f >= 8) val = cond[(f - 8) * 2 + (j & 1)];
            }
            w[jj] = (short)f2b(val);
        }
        *(short4v*)(fr + CIMG + tid * 4) = w;
    }
}

// ---------------- transpose fp32 [K][N] -> bf16 [N][ldt] ----------------
__global__ __launch_bounds__(256) void transpose_bf16_kernel(
    const float* __restrict__ W, u16* __restrict__ Wt, int K, int N, int ldt)
{
    __shared__ float t[32][33];
    int n0 = blockIdx.x * 32, k0 = blockIdx.y * 32;
    int x = threadIdx.x & 31, y0 = threadIdx.x >> 5;   // 32x8
    for (int yy = y0; yy < 32; yy += 8) {
        int k = k0 + yy, n = n0 + x;
        t[yy][x] = (k < K && n < N) ? W[(size_t)k * N + n] : 0.f;
    }
    __syncthreads();
    for (int yy = y0; yy < 32; yy += 8) {
        int n = n0 + yy, k = k0 + x;
        if (n < N && k < ldt) Wt[(size_t)n * ldt + k] = f2b(t[x][yy]);
    }
}

// ---------------- GEMM: C[M][N] = A[M][K] @ Bt[N][K]^T  (bf16 in, f32 acc) ----------------
// EPI 0: +bias, tanh-GELU -> bf16       EPI 1: +bias -> bf16
// EPI 2: +bias + resid -> f32 (rows < Mvalid)
template<int EPI, int BN>
__global__ __launch_bounds__(256) void gemm_kernel(
    const u16* __restrict__ A, const u16* __restrict__ Bt,
    const float* __restrict__ bias, const float* __restrict__ resid,
    u16* __restrict__ Cb, float* __restrict__ Cf,
    int N, int K, int Mvalid)
{
    __shared__ u16 As[128 * 32];
    __shared__ u16 Bs[BN * 32];
    constexpr int NJ = BN / 32;
    const int tid = threadIdx.x;
    const int lane = tid & 63, wid = tid >> 6;
    const int l15 = lane & 15, l4 = lane >> 4;
    const int m0 = blockIdx.y * 128, n0 = blockIdx.x * BN;
    const int wr = (wid >> 1) * 64, wc = (wid & 1) * (BN / 2);

    f32x4 acc[4][NJ];
#pragma unroll
    for (int i = 0; i < 4; i++)
#pragma unroll
        for (int j = 0; j < NJ; j++) acc[i][j] = (f32x4){0.f, 0.f, 0.f, 0.f};

    const int r0 = tid >> 2, sg = (tid & 3) * 8;

    for (int k0 = 0; k0 < K; k0 += 32) {
        __syncthreads();
        gload16(A + (size_t)(m0 + r0) * K + k0 + sg, (char*)As + tid * 16);
        gload16(A + (size_t)(m0 + r0 + 64) * K + k0 + sg, (char*)As + tid * 16 + 4096);
        gload16(Bt + (size_t)(n0 + r0) * K + k0 + sg, (char*)Bs + tid * 16);
        if (BN == 128)
            gload16(Bt + (size_t)(n0 + r0 + 64) * K + k0 + sg, (char*)Bs + tid * 16 + 4096);
        __syncthreads();
        short8 af[4], bfr[NJ];
#pragma unroll
        for (int i = 0; i < 4; i++)
            af[i] = *(const short8*)(&As[(wr + i * 16 + l15) * 32 + l4 * 8]);
#pragma unroll
        for (int j = 0; j < NJ; j++)
            bfr[j] = *(const short8*)(&Bs[(wc + j * 16 + l15) * 32 + l4 * 8]);
#pragma unroll
        for (int i = 0; i < 4; i++)
#pragma unroll
            for (int j = 0; j < NJ; j++)
                acc[i][j] = __builtin_amdgcn_mfma_f32_16x16x32_bf16(af[i], bfr[j], acc[i][j], 0, 0, 0);
    }

#pragma unroll
    for (int i = 0; i < 4; i++) {
#pragma unroll
        for (int j = 0; j < NJ; j++) {
#pragma unroll
            for (int r = 0; r < 4; r++) {
                int row = m0 + wr + i * 16 + l4 * 4 + r;
                int col = n0 + wc + j * 16 + l15;
                float v = acc[i][j][r] + bias[col];
                if (EPI == 0) {
                    float t = v + 0.044715f * v * v * v;
                    float g = 0.5f * v * (1.0f + tanhf(0.7978845608028654f * t));
                    Cb[(size_t)row * N + col] = f2b(g);
                } else if (EPI == 1) {
                    Cb[(size_t)row * N + col] = f2b(v);
                } else {
                    if (row < Mvalid)
                        Cf[(size_t)row * N + col] = v + resid[(size_t)row * N + col];
                }
            }
        }
    }
}

// ---------------- LayerNorm over 1024 (bf16 -> bf16) ----------------
__global__ __launch_bounds__(256) void ln_kernel(
    const u16* __restrict__ h2, const float* __restrict__ g,
    const float* __restrict__ b, u16* __restrict__ out)
{
    int row = blockIdx.x;
    int tid = threadIdx.x;
    const u16* p = h2 + (size_t)row * DH;
    float v[4];
#pragma unroll
    for (int i = 0; i < 4; i++) v[i] = b2f(p[tid * 4 + i]);
    float s1 = v[0] + v[1] + v[2] + v[3];
    float s2 = v[0]*v[0] + v[1]*v[1] + v[2]*v[2] + v[3]*v[3];
    for (int m = 1; m < 64; m <<= 1) { s1 += __shfl_xor(s1, m); s2 += __shfl_xor(s2, m); }
    __shared__ float a1[4], a2[4];
    int w = tid >> 6;
    if ((tid & 63) == 0) { a1[w] = s1; a2[w] = s2; }
    __syncthreads();
    s1 = a1[0] + a1[1] + a1[2] + a1[3];
    s2 = a2[0] + a2[1] + a2[2] + a2[3];
    float mean = s1 * (1.0f / 1024.0f);
    float var = s2 * (1.0f / 1024.0f) - mean * mean;
    float rs = rsqrtf(var + 1e-5f);
    u16* q = out + (size_t)row * DH;
#pragma unroll
    for (int i = 0; i < 4; i++) {
        int c = tid * 4 + i;
        q[c] = f2b((v[i] - mean) * rs * g[c] + b[c]);
    }
}

// ---------------- RMSNorm q,k + split + V transpose (Q pre-scaled by 1/8) ----------------
__global__ __launch_bounds__(256) void rmsnorm_kernel(
    const u16* __restrict__ qkv, const float* __restrict__ qw, const float* __restrict__ kw,
    u16* __restrict__ qb, u16* __restrict__ kb, u16* __restrict__ vt)
{
    int n = blockIdx.x;
    int lane = threadIdx.x & 63, w = threadIdx.x >> 6;
#pragma unroll
    for (int hh = 0; hh < 4; hh++) {
        int h = w * 4 + hh;
        float qv = b2f(qkv[(size_t)n * 3072 + h * 64 + lane]);
        float kv = b2f(qkv[(size_t)n * 3072 + 1024 + h * 64 + lane]);
        float vv = b2f(qkv[(size_t)n * 3072 + 2048 + h * 64 + lane]);
        float sq = qv * qv, sk = kv * kv;
        for (int m = 1; m < 64; m <<= 1) { sq += __shfl_xor(sq, m); sk += __shfl_xor(sk, m); }
        float rq = rsqrtf(sq * (1.0f / 64.0f) + 1e-6f);
        float rk = rsqrtf(sk * (1.0f / 64.0f) + 1e-6f);
        qb[(size_t)n * DH + h * 64 + lane] = f2b(qv * rq * qw[lane] * 0.125f);  // fold 1/sqrt(64)
        kb[(size_t)n * DH + h * 64 + lane] = f2b(kv * rk * kw[lane]);
        vt[(size_t)(h * 64 + lane) * NKV + n] = f2b(vv);
    }
}

// ---------------- flash attention: 1 wave = 32 queries, swapped-QK 32x32 MFMA ----------------
// S^T = mfma(K, Q): lane holds 16 key-scores of query (lane&31) -> softmax nearly in-register.
__global__ __launch_bounds__(64) void attn_kernel(
    const u16* __restrict__ Q, const u16* __restrict__ Kb,
    const u16* __restrict__ Vt, u16* __restrict__ O)
{
    __shared__ u16 P[32 * 40];           // [q][key] padded to 40 (80B rows, 16B aligned)
    const int bid = blockIdx.x;
    const int qt = bid % QT;
    const int h  = bid / QT;
    const int lane = threadIdx.x;
    const int kq = lane & 31;            // A-row (key) / B-col (query) index
    const int hi = lane >> 5;
    const int q0 = qt * 32;

    short8 qf[4];
#pragma unroll
    for (int s = 0; s < 4; s++)
        qf[s] = *(const short8*)(Q + (size_t)(q0 + kq) * DH + h * 64 + s * 16 + hi * 8);

    f32x16 o0 = {0,0,0,0,0,0,0,0,0,0,0,0,0,0,0,0};
    f32x16 o1 = {0,0,0,0,0,0,0,0,0,0,0,0,0,0,0,0};
    float mr = -3.0e38f, lr = 0.f;

    for (int k0 = 0; k0 < NKV; k0 += 32) {
        f32x16 st = {0,0,0,0,0,0,0,0,0,0,0,0,0,0,0,0};
#pragma unroll
        for (int s = 0; s < 4; s++) {
            short8 kf = *(const short8*)(Kb + (size_t)(k0 + kq) * DH + h * 64 + s * 16 + hi * 8);
            st = __builtin_amdgcn_mfma_f32_32x32x16_bf16(kf, qf[s], st, 0, 0, 0);
        }
        if (k0 + 32 > M_VALID) {         // only last tile
#pragma unroll
            for (int r = 0; r < 16; r++) {
                int key = k0 + (r & 3) + 8 * (r >> 2) + 4 * hi;
                if (key >= M_VALID) st[r] = -3.0e38f;
            }
        }
        float tmax = st[0];
#pragma unroll
        for (int r = 1; r < 16; r++) tmax = fmaxf(tmax, st[r]);
        tmax = fmaxf(tmax, __shfl_xor(tmax, 32));
        if (__any(tmax - mr > 8.0f)) {   // defer-max (T13)
            float mn = fmaxf(mr, tmax);
            float corr = __expf(mr - mn);
            mr = mn;
            lr *= corr;
#pragma unroll
            for (int r = 0; r < 16; r++) { o0[r] *= corr; o1[r] *= corr; }
        }
        float p[16];
        float sum = 0.f;
#pragma unroll
        for (int r = 0; r < 16; r++) { p[r] = __expf(st[r] - mr); sum += p[r]; }
        lr += sum + __shfl_xor(sum, 32);

        // P^T regs -> P_lds[q][key]: 4 groups of 4 consecutive keys each
#pragma unroll
        for (int g = 0; g < 4; g++) {
            short4v w;
#pragma unroll
            for (int e = 0; e < 4; e++) w[e] = (short)f2b(p[g * 4 + e]);
            *(short4v*)((char*)P + kq * 80 + g * 16 + hi * 8) = w;
        }
        // PV: A = P_lds rows (q), B = Vt rows (d)
#pragma unroll
        for (int ks = 0; ks < 2; ks++) {
            short8 pa = *(const short8*)((const char*)P + kq * 80 + ks * 32 + hi * 16);
            short8 vb0 = *(const short8*)(Vt + (size_t)(h * 64 + kq) * NKV + k0 + ks * 16 + hi * 8);
            o0 = __builtin_amdgcn_mfma_f32_32x32x16_bf16(pa, vb0, o0, 0, 0, 0);
            short8 vb1 = *(const short8*)(Vt + (size_t)(h * 64 + 32 + kq) * NKV + k0 + ks * 16 + hi * 8);
            o1 = __builtin_amdgcn_mfma_f32_32x32x16_bf16(pa, vb1, o1, 0, 0, 0);
        }
    }

#pragma unroll
    for (int r = 0; r < 16; r++) {
        int rl = (r & 3) + 8 * (r >> 2) + 4 * hi;
        float lrow = __shfl(lr, rl);
        int qrow = q0 + rl;
        if (qrow < M_VALID) {
            float inv = 1.0f / lrow;
            int mrow = (qrow % 3) * 880 + qrow / 3;   // (S,T) -> (T,S) permute
            O[(size_t)mrow * DH + h * 64 + kq] = f2b(o0[r] * inv);
            O[(size_t)mrow * DH + h * 64 + 32 + kq] = f2b(o1[r] * inv);
        }
    }
}

// ---------------- launch ----------------
extern "C" void kernel_launch(void* const* d_in, const int* in_sizes, int n_in,
                              void* d_out, int out_size, void* d_ws, size_t ws_size,
                              hipStream_t stream)
{
    const float* x      = (const float*)d_in[0];
    const float* cond   = (const float*)d_in[1];
    const float* w1     = (const float*)d_in[2];
    const float* b1     = (const float*)d_in[3];
    const float* w2     = (const float*)d_in[4];
    const float* b2     = (const float*)d_in[5];
    const float* ln_g   = (const float*)d_in[6];
    const float* ln_b   = (const float*)d_in[7];
    const float* wqkv   = (const float*)d_in[8];
    const float* bqkv   = (const float*)d_in[9];
    const float* qn_w   = (const float*)d_in[10];
    const float* kn_w   = (const float*)d_in[11];
    const float* wproj  = (const float*)d_in[12];
    const float* bproj  = (const float*)d_in[13];
    float* out = (float*)d_out;

    char* ws = (char*)d_ws;
    size_t off = 0;
    auto alloc = [&](size_t bytes) { size_t o = off; off += (bytes + 255) & ~(size_t)255; return o; };

    size_t off_fused  = alloc((size_t)M_PAD * K1P * 2);
    size_t off_w1t    = alloc((size_t)DH * K1P * 2);
    size_t off_w2t    = alloc((size_t)DH * DH * 2);
    size_t off_wqkvt  = alloc((size_t)3072 * DH * 2);
    size_t off_wprojt = alloc((size_t)CIMG * DH * 2);
    size_t off_h1     = alloc((size_t)M_PAD * DH * 2);
    size_t off_h2     = alloc((size_t)M_PAD * DH * 2);
    size_t off_h2ln   = alloc((size_t)M_PAD * DH * 2);
    size_t off_qkv    = alloc((size_t)M_PAD * 3072 * 2);
    size_t off_qbf    = alloc((size_t)M_PAD * DH * 2);
    size_t off_kbf    = alloc((size_t)NKV * DH * 2);
    size_t off_vt     = alloc((size_t)DH * NKV * 2);
    size_t off_obf    = alloc((size_t)M_PAD * DH * 2);
    (void)ws_size;

    u16* fused  = (u16*)(ws + off_fused);
    u16* w1t    = (u16*)(ws + off_w1t);
    u16* w2t    = (u16*)(ws + off_w2t);
    u16* wqkvt  = (u16*)(ws + off_wqkvt);
    u16* wprojt = (u16*)(ws + off_wprojt);
    u16* h1     = (u16*)(ws + off_h1);
    u16* h2     = (u16*)(ws + off_h2);
    u16* h2ln   = (u16*)(ws + off_h2ln);
    u16* qkvb   = (u16*)(ws + off_qkv);
    u16* qbf    = (u16*)(ws + off_qbf);
    u16* kbf    = (u16*)(ws + off_kbf);
    u16* vt     = (u16*)(ws + off_vt);
    u16* obf    = (u16*)(ws + off_obf);

    // zero pad regions (re-done every launch: deterministic)
    hipMemsetAsync(ws + off_fused + (size_t)M_VALID * K1P * 2, 0, (size_t)(M_PAD - M_VALID) * K1P * 2, stream);
    hipMemsetAsync(ws + off_qbf + (size_t)M_VALID * DH * 2, 0, (size_t)(M_PAD - M_VALID) * DH * 2, stream);
    hipMemsetAsync(ws + off_kbf + (size_t)M_VALID * DH * 2, 0, (size_t)(NKV - M_VALID) * DH * 2, stream);
    hipMemsetAsync(ws + off_vt, 0, (size_t)DH * NKV * 2, stream);
    hipMemsetAsync(ws + off_obf + (size_t)M_VALID * DH * 2, 0, (size_t)(M_PAD - M_VALID) * DH * 2, stream);

    build_fused_kernel<<<M_VALID, 256, 0, stream>>>(x, cond, fused);
    transpose_bf16_kernel<<<dim3(DH / 32, K1P / 32), 256, 0, stream>>>(w1, w1t, K1, DH, K1P);
    transpose_bf16_kernel<<<dim3(DH / 32, DH / 32), 256, 0, stream>>>(w2, w2t, DH, DH, DH);
    transpose_bf16_kernel<<<dim3(3072 / 32, DH / 32), 256, 0, stream>>>(wqkv, wqkvt, DH, 3072, DH);
    transpose_bf16_kernel<<<dim3(CIMG / 32, DH / 32), 256, 0, stream>>>(wproj, wprojt, DH, CIMG, DH);

    gemm_kernel<0, 64><<<dim3(DH / 64, M_PAD / 128), 256, 0, stream>>>(fused, w1t, b1, nullptr, h1, nullptr, DH, K1P, M_PAD);
    gemm_kernel<1, 64><<<dim3(DH / 64, M_PAD / 128), 256, 0, stream>>>(h1, w2t, b2, nullptr, h2, nullptr, DH, DH, M_PAD);
    ln_kernel<<<M_PAD, 256, 0, stream>>>(h2, ln_g, ln_b, h2ln);
    gemm_kernel<1, 128><<<dim3(3072 / 128, M_PAD / 128), 256, 0, stream>>>(h2ln, wqkvt, bqkv, nullptr, qkvb, nullptr, 3072, DH, M_PAD);
    rmsnorm_kernel<<<M_VALID, 256, 0, stream>>>(qkvb, qn_w, kn_w, qbf, kbf, vt);
    attn_kernel<<<dim3(QT * NHEAD), 64, 0, stream>>>(qbf, kbf, vt, obf);
    gemm_kernel<2, 128><<<dim3(CIMG / 128, M_PAD / 128), 256, 0, stream>>>(obf, wprojt, bproj, x, nullptr, out, CIMG, DH, M_VALID);
}

// Round 3
// 321.700 us; speedup vs baseline: 1.3016x; 1.0658x over previous
//
#include <hip/hip_runtime.h>
#include <hip/hip_bf16.h>

typedef __attribute__((ext_vector_type(8))) short short8;
typedef __attribute__((ext_vector_type(4))) short short4v;
typedef __attribute__((ext_vector_type(4))) float f32x4;
typedef __attribute__((ext_vector_type(16))) float f32x16;
typedef unsigned short u16;

#define ZERO16 (f32x16){0,0,0,0,0,0,0,0,0,0,0,0,0,0,0,0}

__device__ __forceinline__ float b2f(u16 h) {
    unsigned u = ((unsigned)h) << 16;
    float f; __builtin_memcpy(&f, &u, 4); return f;
}
__device__ __forceinline__ u16 f2b(float f) {
    unsigned u; __builtin_memcpy(&u, &f, 4);
    unsigned r = u + 0x7FFFu + ((u >> 16) & 1u);
    return (u16)(r >> 16);
}
__device__ __forceinline__ void gload16(const void* g, void* l) {
    __builtin_amdgcn_global_load_lds(
        (const __attribute__((address_space(1))) unsigned*)g,
        (__attribute__((address_space(3))) unsigned*)l, 16, 0, 0);
}

// ---------------- problem constants ----------------
#define M_VALID 2640          // B*S*T tokens
#define M_PAD   2688          // 21 * 128
#define K1      3096          // 3072 + 24
#define K1P     3104          // padded to multiple of 32
#define DH      1024
#define CIMG    3072
#define NKV     2656          // 83 * 32 (kv padded)
#define NHEAD   16
#define QT      83            // ceil(2640/32) q-tiles

// ---------------- build fused input (bf16) ----------------
__global__ __launch_bounds__(256) void build_fused_kernel(
    const float* __restrict__ x, const float* __restrict__ cond,
    u16* __restrict__ fused)
{
    int n = blockIdx.x;
    int tid = threadIdx.x;
    const float* xr = x + (size_t)n * CIMG;
    u16* fr = fused + (size_t)n * K1P;
    for (int c = tid * 4; c < CIMG; c += 1024) {
        float4 v = *(const float4*)(xr + c);
        short4v w;
        w[0] = (short)f2b(v.x); w[1] = (short)f2b(v.y);
        w[2] = (short)f2b(v.z); w[3] = (short)f2b(v.w);
        *(short4v*)(fr + c) = w;
    }
    if (tid < 8) {
        int t = n % 3;
        short4v w;
        for (int jj = 0; jj < 4; jj++) {
            int j = tid * 4 + jj;
            float val = 0.f;
            if (j < 24) {
                int f = t * 4 + (j >> 1);          // row in mouse_padded (20 rows, first 8 zero)
                if (f >= 8) val = cond[(f - 8) * 2 + (j & 1)];
            }
            w[jj] = (short)f2b(val);
        }
        *(short4v*)(fr + CIMG + tid * 4) = w;
    }
}

// ---------------- transpose fp32 [K][N] -> bf16 [N][ldt] ----------------
__global__ __launch_bounds__(256) void transpose_bf16_kernel(
    const float* __restrict__ W, u16* __restrict__ Wt, int K, int N, int ldt)
{
    __shared__ float t[32][33];
    int n0 = blockIdx.x * 32, k0 = blockIdx.y * 32;
    int x = threadIdx.x & 31, y0 = threadIdx.x >> 5;   // 32x8
    for (int yy = y0; yy < 32; yy += 8) {
        int k = k0 + yy, n = n0 + x;
        t[yy][x] = (k < K && n < N) ? W[(size_t)k * N + n] : 0.f;
    }
    __syncthreads();
    for (int yy = y0; yy < 32; yy += 8) {
        int n = n0 + yy, k = k0 + x;
        if (n < N && k < ldt) Wt[(size_t)n * ldt + k] = f2b(t[x][yy]);
    }
}

// ---------------- GEMM: C[M][N] = A[M][K] @ Bt[N][K]^T  (bf16 in, f32 acc) ----------------
// EPI 0: +bias, tanh-GELU -> bf16       EPI 1: +bias -> bf16
// EPI 2: +bias + resid -> f32 (rows < Mvalid)
template<int EPI, int BN>
__global__ __launch_bounds__(256) void gemm_kernel(
    const u16* __restrict__ A, const u16* __restrict__ Bt,
    const float* __restrict__ bias, const float* __restrict__ resid,
    u16* __restrict__ Cb, float* __restrict__ Cf,
    int N, int K, int Mvalid)
{
    __shared__ u16 As[128 * 32];
    __shared__ u16 Bs[BN * 32];
    constexpr int NJ = BN / 32;
    const int tid = threadIdx.x;
    const int lane = tid & 63, wid = tid >> 6;
    const int l15 = lane & 15, l4 = lane >> 4;
    const int m0 = blockIdx.y * 128, n0 = blockIdx.x * BN;
    const int wr = (wid >> 1) * 64, wc = (wid & 1) * (BN / 2);

    f32x4 acc[4][NJ];
#pragma unroll
    for (int i = 0; i < 4; i++)
#pragma unroll
        for (int j = 0; j < NJ; j++) acc[i][j] = (f32x4){0.f, 0.f, 0.f, 0.f};

    const int r0 = tid >> 2, sg = (tid & 3) * 8;

    for (int k0 = 0; k0 < K; k0 += 32) {
        __syncthreads();
        gload16(A + (size_t)(m0 + r0) * K + k0 + sg, (char*)As + tid * 16);
        gload16(A + (size_t)(m0 + r0 + 64) * K + k0 + sg, (char*)As + tid * 16 + 4096);
        gload16(Bt + (size_t)(n0 + r0) * K + k0 + sg, (char*)Bs + tid * 16);
        if (BN == 128)
            gload16(Bt + (size_t)(n0 + r0 + 64) * K + k0 + sg, (char*)Bs + tid * 16 + 4096);
        __syncthreads();
        short8 af[4], bfr[NJ];
#pragma unroll
        for (int i = 0; i < 4; i++)
            af[i] = *(const short8*)(&As[(wr + i * 16 + l15) * 32 + l4 * 8]);
#pragma unroll
        for (int j = 0; j < NJ; j++)
            bfr[j] = *(const short8*)(&Bs[(wc + j * 16 + l15) * 32 + l4 * 8]);
#pragma unroll
        for (int i = 0; i < 4; i++)
#pragma unroll
            for (int j = 0; j < NJ; j++)
                acc[i][j] = __builtin_amdgcn_mfma_f32_16x16x32_bf16(af[i], bfr[j], acc[i][j], 0, 0, 0);
    }

#pragma unroll
    for (int i = 0; i < 4; i++) {
#pragma unroll
        for (int j = 0; j < NJ; j++) {
#pragma unroll
            for (int r = 0; r < 4; r++) {
                int row = m0 + wr + i * 16 + l4 * 4 + r;
                int col = n0 + wc + j * 16 + l15;
                float v = acc[i][j][r] + bias[col];
                if (EPI == 0) {
                    float t = v + 0.044715f * v * v * v;
                    float g = 0.5f * v * (1.0f + tanhf(0.7978845608028654f * t));
                    Cb[(size_t)row * N + col] = f2b(g);
                } else if (EPI == 1) {
                    Cb[(size_t)row * N + col] = f2b(v);
                } else {
                    if (row < Mvalid)
                        Cf[(size_t)row * N + col] = v + resid[(size_t)row * N + col];
                }
            }
        }
    }
}

// ---------------- LayerNorm over 1024 (bf16 -> bf16) ----------------
__global__ __launch_bounds__(256) void ln_kernel(
    const u16* __restrict__ h2, const float* __restrict__ g,
    const float* __restrict__ b, u16* __restrict__ out)
{
    int row = blockIdx.x;
    int tid = threadIdx.x;
    const u16* p = h2 + (size_t)row * DH;
    float v[4];
#pragma unroll
    for (int i = 0; i < 4; i++) v[i] = b2f(p[tid * 4 + i]);
    float s1 = v[0] + v[1] + v[2] + v[3];
    float s2 = v[0]*v[0] + v[1]*v[1] + v[2]*v[2] + v[3]*v[3];
    for (int m = 1; m < 64; m <<= 1) { s1 += __shfl_xor(s1, m); s2 += __shfl_xor(s2, m); }
    __shared__ float a1[4], a2[4];
    int w = tid >> 6;
    if ((tid & 63) == 0) { a1[w] = s1; a2[w] = s2; }
    __syncthreads();
    s1 = a1[0] + a1[1] + a1[2] + a1[3];
    s2 = a2[0] + a2[1] + a2[2] + a2[3];
    float mean = s1 * (1.0f / 1024.0f);
    float var = s2 * (1.0f / 1024.0f) - mean * mean;
    float rs = rsqrtf(var + 1e-5f);
    u16* q = out + (size_t)row * DH;
#pragma unroll
    for (int i = 0; i < 4; i++) {
        int c = tid * 4 + i;
        q[c] = f2b((v[i] - mean) * rs * g[c] + b[c]);
    }
}

// ---------------- RMSNorm q,k + split + V transpose (Q pre-scaled by 1/8) ----------------
__global__ __launch_bounds__(256) void rmsnorm_kernel(
    const u16* __restrict__ qkv, const float* __restrict__ qw, const float* __restrict__ kw,
    u16* __restrict__ qb, u16* __restrict__ kb, u16* __restrict__ vt)
{
    int n = blockIdx.x;
    int lane = threadIdx.x & 63, w = threadIdx.x >> 6;
#pragma unroll
    for (int hh = 0; hh < 4; hh++) {
        int h = w * 4 + hh;
        float qv = b2f(qkv[(size_t)n * 3072 + h * 64 + lane]);
        float kv = b2f(qkv[(size_t)n * 3072 + 1024 + h * 64 + lane]);
        float vv = b2f(qkv[(size_t)n * 3072 + 2048 + h * 64 + lane]);
        float sq = qv * qv, sk = kv * kv;
        for (int m = 1; m < 64; m <<= 1) { sq += __shfl_xor(sq, m); sk += __shfl_xor(sk, m); }
        float rq = rsqrtf(sq * (1.0f / 64.0f) + 1e-6f);
        float rk = rsqrtf(sk * (1.0f / 64.0f) + 1e-6f);
        qb[(size_t)n * DH + h * 64 + lane] = f2b(qv * rq * qw[lane] * 0.125f);  // fold 1/sqrt(64)
        kb[(size_t)n * DH + h * 64 + lane] = f2b(kv * rk * kw[lane]);
        vt[(size_t)(h * 64 + lane) * NKV + n] = f2b(vv);
    }
}

// ---------------- attention tile: softmax + PV (shared by both chains) ----------------
__device__ __forceinline__ void attn_tile(
    f32x16& st, float& mr, float& lr, f32x16& o0, f32x16& o1,
    u16* Pbuf, const short8* vv, int kq, int hi)
{
    float tmax = st[0];
#pragma unroll
    for (int r = 1; r < 16; r++) tmax = fmaxf(tmax, st[r]);
    tmax = fmaxf(tmax, __shfl_xor(tmax, 32));
    if (__any(tmax - mr > 8.0f)) {       // defer-max (T13)
        float mn = fmaxf(mr, tmax);
        float corr = __expf(mr - mn);
        mr = mn; lr *= corr;
#pragma unroll
        for (int r = 0; r < 16; r++) {   // per-O-row factor: O rows are query rl, not kq
            float cr = __shfl(corr, (r & 3) + 8 * (r >> 2) + 4 * hi);
            o0[r] *= cr; o1[r] *= cr;
        }
    }
    float sum = 0.f;
    float p[16];
#pragma unroll
    for (int r = 0; r < 16; r++) { p[r] = __expf(st[r] - mr); sum += p[r]; }
    lr += sum + __shfl_xor(sum, 32);
#pragma unroll
    for (int g = 0; g < 4; g++) {
        short4v w;
#pragma unroll
        for (int e = 0; e < 4; e++) w[e] = (short)f2b(p[g * 4 + e]);
        *(short4v*)((char*)Pbuf + kq * 80 + g * 16 + hi * 8) = w;
    }
    short8 pa0 = *(const short8*)((const char*)Pbuf + kq * 80 + hi * 16);
    short8 pa1 = *(const short8*)((const char*)Pbuf + kq * 80 + 32 + hi * 16);
    o0 = __builtin_amdgcn_mfma_f32_32x32x16_bf16(pa0, vv[0], o0, 0, 0, 0);
    o0 = __builtin_amdgcn_mfma_f32_32x32x16_bf16(pa1, vv[1], o0, 0, 0, 0);
    o1 = __builtin_amdgcn_mfma_f32_32x32x16_bf16(pa0, vv[2], o1, 0, 0, 0);
    o1 = __builtin_amdgcn_mfma_f32_32x32x16_bf16(pa1, vv[3], o1, 0, 0, 0);
}

// ---------------- flash attention: 1 wave = 32 queries, 2 interleaved key-chains ----------------
__global__ __launch_bounds__(64, 2) void attn_kernel(
    const u16* __restrict__ Q, const u16* __restrict__ Kb,
    const u16* __restrict__ Vt, u16* __restrict__ O)
{
    __shared__ u16 PA[32 * 40], PB[32 * 40];
    const int bid = blockIdx.x;
    const int qt = bid % QT;
    const int h  = bid / QT;
    const int lane = threadIdx.x;
    const int kq = lane & 31;
    const int hi = lane >> 5;
    const int q0 = qt * 32;
    const u16* Kh = Kb + h * 64;
    const u16* V0 = Vt + (size_t)(h * 64 + kq) * NKV;
    const u16* V1 = Vt + (size_t)(h * 64 + 32 + kq) * NKV;

    short8 qf[4];
#pragma unroll
    for (int s = 0; s < 4; s++)
        qf[s] = *(const short8*)(Q + (size_t)(q0 + kq) * DH + h * 64 + s * 16 + hi * 8);

    f32x16 oA0 = ZERO16, oA1 = ZERO16, oB0 = ZERO16, oB1 = ZERO16;
    float mA = -3.0e38f, lA = 0.f, mB = -3.0e38f, lB = 0.f;

    // ---- masked tail tile (keys 2624..2655) into chain A ----
    {
        const int k0 = 2624;
        short8 kf[4];
#pragma unroll
        for (int s = 0; s < 4; s++)
            kf[s] = *(const short8*)(Kh + (size_t)(k0 + kq) * DH + s * 16 + hi * 8);
        short8 vv[4];
        vv[0] = *(const short8*)(V0 + k0 + hi * 8);
        vv[1] = *(const short8*)(V0 + k0 + 16 + hi * 8);
        vv[2] = *(const short8*)(V1 + k0 + hi * 8);
        vv[3] = *(const short8*)(V1 + k0 + 16 + hi * 8);
        f32x16 st = ZERO16;
#pragma unroll
        for (int s = 0; s < 4; s++)
            st = __builtin_amdgcn_mfma_f32_32x32x16_bf16(kf[s], qf[s], st, 0, 0, 0);
#pragma unroll
        for (int r = 0; r < 16; r++) {
            int key = k0 + (r & 3) + 8 * (r >> 2) + 4 * hi;
            if (key >= M_VALID) st[r] = -3.0e38f;
        }
        attn_tile(st, mA, lA, oA0, oA1, PA, vv, kq, hi);
    }

    // ---- prefetch K for first main iteration ----
    short8 kA[4], kB[4];
#pragma unroll
    for (int s = 0; s < 4; s++) {
        kA[s] = *(const short8*)(Kh + (size_t)(0 + kq) * DH + s * 16 + hi * 8);
        kB[s] = *(const short8*)(Kh + (size_t)(32 + kq) * DH + s * 16 + hi * 8);
    }

    for (int i = 0; i < 41; i++) {
        const int k0a = i * 64, k0b = k0a + 32;
        short8 vA[4], vB[4];
        vA[0] = *(const short8*)(V0 + k0a + hi * 8);
        vA[1] = *(const short8*)(V0 + k0a + 16 + hi * 8);
        vA[2] = *(const short8*)(V1 + k0a + hi * 8);
        vA[3] = *(const short8*)(V1 + k0a + 16 + hi * 8);
        vB[0] = *(const short8*)(V0 + k0b + hi * 8);
        vB[1] = *(const short8*)(V0 + k0b + 16 + hi * 8);
        vB[2] = *(const short8*)(V1 + k0b + hi * 8);
        vB[3] = *(const short8*)(V1 + k0b + 16 + hi * 8);

        f32x16 stA = ZERO16;
#pragma unroll
        for (int s = 0; s < 4; s++)
            stA = __builtin_amdgcn_mfma_f32_32x32x16_bf16(kA[s], qf[s], stA, 0, 0, 0);
        f32x16 stB = ZERO16;
#pragma unroll
        for (int s = 0; s < 4; s++)
            stB = __builtin_amdgcn_mfma_f32_32x32x16_bf16(kB[s], qf[s], stB, 0, 0, 0);

        if (i < 40) {                    // prefetch next iteration's K tiles
#pragma unroll
            for (int s = 0; s < 4; s++) {
                kA[s] = *(const short8*)(Kh + (size_t)(k0a + 64 + kq) * DH + s * 16 + hi * 8);
                kB[s] = *(const short8*)(Kh + (size_t)(k0b + 64 + kq) * DH + s * 16 + hi * 8);
            }
        }

        attn_tile(stA, mA, lA, oA0, oA1, PA, vA, kq, hi);
        attn_tile(stB, mB, lB, oB0, oB1, PB, vB, kq, hi);
    }

    // ---- merge chains and write (row-permuted) ----
    float m = fmaxf(mA, mB);
    float cA = __expf(mA - m), cB = __expf(mB - m);
    float l = lA * cA + lB * cB;
#pragma unroll
    for (int r = 0; r < 16; r++) {
        int rl = (r & 3) + 8 * (r >> 2) + 4 * hi;
        float cAr = __shfl(cA, rl);
        float cBr = __shfl(cB, rl);
        float lr_ = __shfl(l, rl);
        int qrow = q0 + rl;
        if (qrow < M_VALID) {
            float inv = 1.0f / lr_;
            int mrow = (qrow % 3) * 880 + qrow / 3;   // (S,T) -> (T,S) permute
            O[(size_t)mrow * DH + h * 64 + kq] = f2b((oA0[r] * cAr + oB0[r] * cBr) * inv);
            O[(size_t)mrow * DH + h * 64 + 32 + kq] = f2b((oA1[r] * cAr + oB1[r] * cBr) * inv);
        }
    }
}

// ---------------- launch ----------------
extern "C" void kernel_launch(void* const* d_in, const int* in_sizes, int n_in,
                              void* d_out, int out_size, void* d_ws, size_t ws_size,
                              hipStream_t stream)
{
    const float* x      = (const float*)d_in[0];
    const float* cond   = (const float*)d_in[1];
    const float* w1     = (const float*)d_in[2];
    const float* b1     = (const float*)d_in[3];
    const float* w2     = (const float*)d_in[4];
    const float* b2     = (const float*)d_in[5];
    const float* ln_g   = (const float*)d_in[6];
    const float* ln_b   = (const float*)d_in[7];
    const float* wqkv   = (const float*)d_in[8];
    const float* bqkv   = (const float*)d_in[9];
    const float* qn_w   = (const float*)d_in[10];
    const float* kn_w   = (const float*)d_in[11];
    const float* wproj  = (const float*)d_in[12];
    const float* bproj  = (const float*)d_in[13];
    float* out = (float*)d_out;

    char* ws = (char*)d_ws;
    size_t off = 0;
    auto alloc = [&](size_t bytes) { size_t o = off; off += (bytes + 255) & ~(size_t)255; return o; };

    size_t off_fused  = alloc((size_t)M_PAD * K1P * 2);
    size_t off_w1t    = alloc((size_t)DH * K1P * 2);
    size_t off_w2t    = alloc((size_t)DH * DH * 2);
    size_t off_wqkvt  = alloc((size_t)3072 * DH * 2);
    size_t off_wprojt = alloc((size_t)CIMG * DH * 2);
    size_t off_h1     = alloc((size_t)M_PAD * DH * 2);
    size_t off_h2     = alloc((size_t)M_PAD * DH * 2);
    size_t off_h2ln   = alloc((size_t)M_PAD * DH * 2);
    size_t off_qkv    = alloc((size_t)M_PAD * 3072 * 2);
    size_t off_qbf    = alloc((size_t)M_PAD * DH * 2);
    size_t off_kbf    = alloc((size_t)NKV * DH * 2);
    size_t off_vt     = alloc((size_t)DH * NKV * 2);
    size_t off_obf    = alloc((size_t)M_PAD * DH * 2);
    (void)ws_size;

    u16* fused  = (u16*)(ws + off_fused);
    u16* w1t    = (u16*)(ws + off_w1t);
    u16* w2t    = (u16*)(ws + off_w2t);
    u16* wqkvt  = (u16*)(ws + off_wqkvt);
    u16* wprojt = (u16*)(ws + off_wprojt);
    u16* h1     = (u16*)(ws + off_h1);
    u16* h2     = (u16*)(ws + off_h2);
    u16* h2ln   = (u16*)(ws + off_h2ln);
    u16* qkvb   = (u16*)(ws + off_qkv);
    u16* qbf    = (u16*)(ws + off_qbf);
    u16* kbf    = (u16*)(ws + off_kbf);
    u16* vt     = (u16*)(ws + off_vt);
    u16* obf    = (u16*)(ws + off_obf);

    // zero pad regions (pad K rows must be finite-and-masked; fused pads feed gemm1)
    hipMemsetAsync(ws + off_fused + (size_t)M_VALID * K1P * 2, 0, (size_t)(M_PAD - M_VALID) * K1P * 2, stream);
    hipMemsetAsync(ws + off_kbf + (size_t)M_VALID * DH * 2, 0, (size_t)(NKV - M_VALID) * DH * 2, stream);

    build_fused_kernel<<<M_VALID, 256, 0, stream>>>(x, cond, fused);
    transpose_bf16_kernel<<<dim3(DH / 32, K1P / 32), 256, 0, stream>>>(w1, w1t, K1, DH, K1P);
    transpose_bf16_kernel<<<dim3(DH / 32, DH / 32), 256, 0, stream>>>(w2, w2t, DH, DH, DH);
    transpose_bf16_kernel<<<dim3(3072 / 32, DH / 32), 256, 0, stream>>>(wqkv, wqkvt, DH, 3072, DH);
    transpose_bf16_kernel<<<dim3(CIMG / 32, DH / 32), 256, 0, stream>>>(wproj, wprojt, DH, CIMG, DH);

    gemm_kernel<0, 64><<<dim3(DH / 64, M_PAD / 128), 256, 0, stream>>>(fused, w1t, b1, nullptr, h1, nullptr, DH, K1P, M_PAD);
    gemm_kernel<1, 64><<<dim3(DH / 64, M_PAD / 128), 256, 0, stream>>>(h1, w2t, b2, nullptr, h2, nullptr, DH, DH, M_PAD);
    ln_kernel<<<M_PAD, 256, 0, stream>>>(h2, ln_g, ln_b, h2ln);
    gemm_kernel<1, 128><<<dim3(3072 / 128, M_PAD / 128), 256, 0, stream>>>(h2ln, wqkvt, bqkv, nullptr, qkvb, nullptr, 3072, DH, M_PAD);
    rmsnorm_kernel<<<M_VALID, 256, 0, stream>>>(qkvb, qn_w, kn_w, qbf, kbf, vt);
    attn_kernel<<<dim3(QT * NHEAD), 64, 0, stream>>>(qbf, kbf, vt, obf);
    gemm_kernel<2, 128><<<dim3(CIMG / 128, M_PAD / 128), 256, 0, stream>>>(obf, wprojt, bproj, x, nullptr, out, CIMG, DH, M_VALID);
}